// Round 1
// baseline (752.907 us; speedup 1.0000x reference)
//
#include <hip/hip_runtime.h>

typedef unsigned short u16;
typedef unsigned int   u32;
typedef __attribute__((ext_vector_type(8))) short short8;
typedef __attribute__((ext_vector_type(4))) float f4;

#define BT 8
#define TX 30
#define TY 10

__device__ __forceinline__ float bf2f_u16(u16 h){ u32 i=((u32)h)<<16; float f; __builtin_memcpy(&f,&i,4); return f; }
__device__ __forceinline__ float lo2f(u32 p){ u32 i=p<<16; float f; __builtin_memcpy(&f,&i,4); return f; }
__device__ __forceinline__ float hi2f(u32 p){ u32 i=p&0xffff0000u; float f; __builtin_memcpy(&f,&i,4); return f; }
__device__ __forceinline__ u16 f2bf(float f){ u32 x; __builtin_memcpy(&x,&f,4); u32 r=(x+0x7fffu+((x>>16)&1u))>>16; return (u16)r; }

#if __has_builtin(__builtin_amdgcn_rcpf)
__device__ __forceinline__ float frcp(float x){ return __builtin_amdgcn_rcpf(x); }
#else
__device__ __forceinline__ float frcp(float x){ return 1.0f/x; }
#endif
// fast activations: single v_exp + v_rcp (no fp32 div sequence)
__device__ __forceinline__ float sigm(float x){ return frcp(1.0f+__expf(-x)); }
__device__ __forceinline__ float tanh_(float x){ x=fminf(fmaxf(x,-15.0f),15.0f); float e=__expf(2.0f*x); return 1.0f - 2.0f*frcp(e+1.0f); }

__device__ __forceinline__ f4 mfma16(short8 a, short8 b, f4 c){
    return __builtin_amdgcn_mfma_f32_16x16x32_bf16(a, b, c, 0, 0, 0);
}

union S8u { short8 s; u32 u[4]; };

// pack hi-halves of two fp32 into one u32 (truncated bf16 pair), residual -> lo pair
__device__ __forceinline__ void cvt_pair(float a0, float a1, u32& hp, u32& lp){
    u32 u0, u1; __builtin_memcpy(&u0,&a0,4); __builtin_memcpy(&u1,&a1,4);
    hp = __builtin_amdgcn_perm(u1, u0, 0x07060302u);          // [hi16(a1) : hi16(a0)]
    float r0 = a0 - hi2f(u0);
    float r1 = a1 - hi2f(u1);
    u32 v0, v1; __builtin_memcpy(&v0,&r0,4); __builtin_memcpy(&v1,&r1,4);
    lp = __builtin_amdgcn_perm(v1, v0, 0x07060302u);
}

struct SDec {
    float aW1[BT][TX][10];      // b1 + a @ W1[:, :64].T  (ty-invariant), computed via MFMA
    u16 sh[BT][72], sl[BT][72]; // s hi/lo bf16, A-frag rows 0-7 (rows 8-15 -> zr2)
    u16 ctxh[BT][72], ctxl[BT][72];
    u16 zr2[72];                // always-zero row (decoder A-frag filler for mL>=8)
    float sW1[BT][12];
    float en[BT][32];
    float w2b[12]; float b2s;
};
struct SEnc {
    u16 h[2][2][2][BT][40];     // [parity][dir][hi/lo][m][k], K=32 pad 40
    u16 zr[40];                 // always-zero row (A-frag filler)
};
union UU { SEnc e; SDec d; };
struct Smem {
    u16 a[BT][TX][72];          // encoder outputs bf16 (pad 72: 144B rows keep 16B align)
    UU u;
};
// LDS: 34560 + max(5200, 15812) ~= 50.4 KB -> 3 blocks/CU

__global__ __launch_bounds__(256, 3) void fused_kernel(
    const float* __restrict__ X,
    const float* __restrict__ Wihf, const float* __restrict__ Whhf, const float* __restrict__ bfv,
    const float* __restrict__ Wihr, const float* __restrict__ Whhr, const float* __restrict__ brv,
    const float* __restrict__ W1, const float* __restrict__ b1, const float* __restrict__ W2, const float* __restrict__ b2,
    const float* __restrict__ Wihp, const float* __restrict__ Whhp, const float* __restrict__ bp,
    const float* __restrict__ Wo, const float* __restrict__ bo,
    float* __restrict__ out)
{
    __shared__ __align__(16) Smem sm;
    const int tid = threadIdx.x;
    const int b0  = blockIdx.x * BT;

    {   // zero only the encoder union region (h bufs + zr must start 0)
        u32* p = (u32*)&sm.u.e;
        for (int i = tid; i < (int)(sizeof(SEnc)/4); i += 256) p[i] = 0u;
    }
    __syncthreads();

    const int lane = tid & 63;
    const int wv   = tid >> 6;     // wave 0..3
    const int mL   = lane & 15;    // frag non-K index
    const int qL   = lane >> 4;    // quad
    const int k0q  = qL * 8;
    const int ed   = wv >> 1;      // encoder dir
    const int ub   = (wv & 1) * 16;// encoder unit base within NA=32
    const int sstep= mL >> 3;      // 0: step t rows, 1: step t+1 rows

    // ===================== encoder =====================
    const float* Wih = ed ? Wihr : Wihf;
    const float* Whh = ed ? Whhr : Whhf;
    const float* bv  = ed ? brv  : bfv;

    short8 Bih[4][4]; short8 Bhh[4]; float bias4[4];
    #pragma unroll
    for (int gt = 0; gt < 4; gt++){
        const int n = gt*32 + ub + mL;                  // gate row (i,f,g,o chunks of 32)
        #pragma unroll
        for (int kt = 0; kt < 4; kt++){
            const float* p = Wih + n*128 + kt*32 + k0q;
            short8 s;
            #pragma unroll
            for (int j = 0; j < 8; j++) s[j] = (short)f2bf(p[j]);
            Bih[gt][kt] = s;
        }
        {
            const float* p = Whh + n*32 + k0q;
            short8 s;
            #pragma unroll
            for (int j = 0; j < 8; j++) s[j] = (short)f2bf(p[j]);
            Bhh[gt] = s;
        }
        bias4[gt] = bv[n];
    }

    const float* xrow = X + ((long)(b0 + (mL & 7))) * TX * 128;  // rows 8-15: same batch row, step t+1
    float cst[4] = {0.f,0.f,0.f,0.f};  // c-state: lives in qL<2 lanes before even steps, swaps via shfl_xor 32

    // pair processor: steps (t, t+1); M rows 0-7 = step t, 8-15 = step t+1
    auto epair = [&](int t, f4* cur, f4* nxt){
        if (t + 2 < TX){                                 // prefetch next pair
            const int ts = ed ? (TX-1-(t+2+sstep)) : (t+2+sstep);
            const float* p = xrow + ts*128 + k0q;
            #pragma unroll
            for (int kt = 0; kt < 4; kt++){
                nxt[2*kt]   = *(const f4*)(p + kt*32);
                nxt[2*kt+1] = *(const f4*)(p + kt*32 + 4);
            }
        }
        const int rb = (t+1) & 1, wb = t & 1;            // h_{t-1} in buf rb; h_t -> buf wb; h_{t+1} -> buf rb

        f4 acc[4];
        #pragma unroll
        for (int gt = 0; gt < 4; gt++) acc[gt] = (f4){bias4[gt],bias4[gt],bias4[gt],bias4[gt]};

        #pragma unroll
        for (int kt = 0; kt < 4; kt++){                  // x-GEMM, both steps at once
            S8u xh, xl;
            #pragma unroll
            for (int pp = 0; pp < 4; pp++){
                const f4 v = cur[2*kt + (pp>>1)];
                const int e = (pp & 1) * 2;
                cvt_pair(v[e], v[e+1], xh.u[pp], xl.u[pp]);
            }
            #pragma unroll
            for (int gt = 0; gt < 4; gt++){
                acc[gt] = mfma16(xh.s, Bih[gt][kt], acc[gt]);
                acc[gt] = mfma16(xl.s, Bih[gt][kt], acc[gt]);
            }
        }
        {   // h-MFMA step t: A rows 0-7 = h_{t-1}, rows 8-15 = 0
            const short8 Ahh = *(const short8*)((mL < 8) ? &sm.u.e.h[rb][ed][0][mL][k0q] : &sm.u.e.zr[k0q]);
            const short8 Ahl = *(const short8*)((mL < 8) ? &sm.u.e.h[rb][ed][1][mL][k0q] : &sm.u.e.zr[k0q]);
            #pragma unroll
            for (int gt = 0; gt < 4; gt++){
                acc[gt] = mfma16(Ahh, Bhh[gt], acc[gt]);
                acc[gt] = mfma16(Ahl, Bhh[gt], acc[gt]);
            }
        }
        if (qL < 2){                                     // cell update step t (rows 0-7)
            const int tpos = ed ? (TX-1-t) : t;
            #pragma unroll
            for (int reg = 0; reg < 4; reg++){
                const int m = qL*4 + reg;
                const float ii = sigm(acc[0][reg]), ff = sigm(acc[1][reg]);
                const float gg = tanh_(acc[2][reg]), oo = sigm(acc[3][reg]);
                cst[reg] = ff*cst[reg] + ii*gg;
                const float hh = oo * tanh_(cst[reg]);
                const u16 hhi = f2bf(hh);
                const u16 hlo = f2bf(hh - bf2f_u16(hhi));
                sm.u.e.h[wb][ed][0][m][ub+mL] = hhi;
                sm.u.e.h[wb][ed][1][m][ub+mL] = hlo;
                sm.a[m][tpos][ed*32 + ub + mL] = hhi;
            }
        }
        #pragma unroll
        for (int reg = 0; reg < 4; reg++) cst[reg] = __shfl_xor(cst[reg], 32);  // c -> qL>=2 lanes
        __syncthreads();
        {   // h-MFMA step t+1: A rows 8-15 = h_t, rows 0-7 = 0
            const short8 Ahh = *(const short8*)((mL >= 8) ? &sm.u.e.h[wb][ed][0][mL-8][k0q] : &sm.u.e.zr[k0q]);
            const short8 Ahl = *(const short8*)((mL >= 8) ? &sm.u.e.h[wb][ed][1][mL-8][k0q] : &sm.u.e.zr[k0q]);
            #pragma unroll
            for (int gt = 0; gt < 4; gt++){
                acc[gt] = mfma16(Ahh, Bhh[gt], acc[gt]);
                acc[gt] = mfma16(Ahl, Bhh[gt], acc[gt]);
            }
        }
        if (qL >= 2){                                    // cell update step t+1 (rows 8-15)
            const int tpos = ed ? (TX-2-t) : (t+1);
            #pragma unroll
            for (int reg = 0; reg < 4; reg++){
                const int m = (qL-2)*4 + reg;
                const float ii = sigm(acc[0][reg]), ff = sigm(acc[1][reg]);
                const float gg = tanh_(acc[2][reg]), oo = sigm(acc[3][reg]);
                cst[reg] = ff*cst[reg] + ii*gg;
                const float hh = oo * tanh_(cst[reg]);
                const u16 hhi = f2bf(hh);
                const u16 hlo = f2bf(hh - bf2f_u16(hhi));
                sm.u.e.h[rb][ed][0][m][ub+mL] = hhi;
                sm.u.e.h[rb][ed][1][m][ub+mL] = hlo;
                sm.a[m][tpos][ed*32 + ub + mL] = hhi;
            }
        }
        #pragma unroll
        for (int reg = 0; reg < 4; reg++) cst[reg] = __shfl_xor(cst[reg], 32);  // c -> qL<2 lanes
        __syncthreads();
    };

    f4 rawA[8], rawB[8];
    {   // initial pair load
        const int ts0 = ed ? (TX-1-sstep) : sstep;
        const float* p = xrow + ts0*128 + k0q;
        #pragma unroll
        for (int kt = 0; kt < 4; kt++){
            rawA[2*kt]   = *(const f4*)(p + kt*32);
            rawA[2*kt+1] = *(const f4*)(p + kt*32 + 4);
        }
    }
    for (int tp = 0; tp < 28; tp += 4){ epair(tp, rawA, rawB); epair(tp+2, rawB, rawA); }
    epair(28, rawA, rawB);                               // last pair (no prefetch)

    // ===================== decoder setup =====================
    {   // zero sh, sl, ctxh, ctxl, zr2 (contiguous block)
        u32* z = (u32*)sm.u.d.sh;
        for (int i = tid; i < (4*BT*72 + 72)/2; i += 256) z[i] = 0u;
    }
    if (tid < 10) sm.u.d.w2b[tid] = W2[tid];
    if (tid == 0) sm.u.d.b2s = b2[0];

    // B-frags for aW1 = b1 + a @ W1[:, :64].T  (hi/lo split of W1 for fp32-class accuracy)
    short8 W1aB[2][2];
    #pragma unroll
    for (int kt = 0; kt < 2; kt++){
        short8 hv8, lv8;
        #pragma unroll
        for (int j = 0; j < 8; j++){
            const float v = (mL < 10) ? W1[mL*128 + kt*32 + k0q + j] : 0.f;
            const u16 hb = f2bf(v);
            hv8[j] = (short)hb;
            lv8[j] = (short)f2bf(v - bf2f_u16(hb));
        }
        W1aB[kt][0] = hv8; W1aB[kt][1] = lv8;
    }
    const float b1v = (mL < 10) ? b1[mL] : 0.f;

    // aW1 via MFMA: M=240 rows (r = b*30 + t), N=10, K=64; a rows contiguous at stride 72 u16
    for (int tile = wv; tile < 15; tile += 4){
        f4 accA = (f4){b1v, b1v, b1v, b1v};
        const u16* abase = &sm.a[0][0][0] + (tile*16 + mL)*72;
        #pragma unroll
        for (int kt = 0; kt < 2; kt++){
            const short8 av = *(const short8*)(abase + kt*32 + k0q);
            accA = mfma16(av, W1aB[kt][0], accA);
            accA = mfma16(av, W1aB[kt][1], accA);
        }
        if (mL < 10){
            #pragma unroll
            for (int reg = 0; reg < 4; reg++){
                const int r = tile*16 + qL*4 + reg;      // r < 240 always (15*16 = 240)
                (&sm.u.d.aW1[0][0][0])[r*10 + mL] = accA[reg];
            }
        }
    }

    const int uw = wv * 16;                              // decoder unit base (NS=64 over 4 waves)
    short8 Bip[4][2], Bhp[4][2]; float pb4[4];
    #pragma unroll
    for (int gt = 0; gt < 4; gt++){
        const int n = gt*64 + uw + mL;                   // post-cell gate row (chunks of 64)
        #pragma unroll
        for (int kt = 0; kt < 2; kt++){
            const float* p = Wihp + n*64 + kt*32 + k0q;
            const float* q = Whhp + n*64 + kt*32 + k0q;
            short8 s1v, s2v;
            #pragma unroll
            for (int j = 0; j < 8; j++){ s1v[j] = (short)f2bf(p[j]); s2v[j] = (short)f2bf(q[j]); }
            Bip[gt][kt] = s1v; Bhp[gt][kt] = s2v;
        }
        pb4[gt] = bp[n];
    }
    short8 Bo2[2];
    {
        const int n = uw + mL;
        #pragma unroll
        for (int kt = 0; kt < 2; kt++){
            const float* p = Wo + n*64 + kt*32 + k0q;
            short8 s;
            #pragma unroll
            for (int j = 0; j < 8; j++) s[j] = (short)f2bf(p[j]);
            Bo2[kt] = s;
        }
    }
    short8 W1sB[2];                                      // B-frag of W1[:,64:128], n=mL (rows>=10 zero)
    #pragma unroll
    for (int kt = 0; kt < 2; kt++){
        short8 s;
        #pragma unroll
        for (int j = 0; j < 8; j++){
            const float v = (mL < 10) ? W1[mL*128 + 64 + kt*32 + k0q + j] : 0.f;
            s[j] = (short)f2bf(v);
        }
        W1sB[kt] = s;
    }
    const float boL = bo[uw + mL];
    float cs2[4] = {0.f,0.f,0.f,0.f};
    __syncthreads();

    // ===================== decoder loop =====================
    for (int ty = 0; ty < TY; ty++){
        {   // sW1 = s @ W1[:,64:].T via MFMA (4 MFMAs, all waves redundantly)
            f4 accW = (f4){0.f,0.f,0.f,0.f};
            #pragma unroll
            for (int kt = 0; kt < 2; kt++){
                const int ko = kt*32 + k0q;
                const short8 shh = *(const short8*)((mL < 8) ? &sm.u.d.sh[mL][ko] : &sm.u.d.zr2[ko]);
                const short8 sll = *(const short8*)((mL < 8) ? &sm.u.d.sl[mL][ko] : &sm.u.d.zr2[ko]);
                accW = mfma16(shh, W1sB[kt], accW);
                accW = mfma16(sll, W1sB[kt], accW);
            }
            if (qL < 2 && mL < 10 && wv == 0){
                #pragma unroll
                for (int reg = 0; reg < 4; reg++) sm.u.d.sW1[qL*4+reg][mL] = accW[reg];
            }
        }
        __syncthreads();
        if (tid < 240){                                  // en = relu(tanh(aW1+sW1) . w2 + b2)
            const int er = tid/30, et = tid - er*30;
            float env = sm.u.d.b2s;
            #pragma unroll
            for (int j = 0; j < 10; j++){
                const float z = sm.u.d.aW1[er][et][j] + sm.u.d.sW1[er][j];
                env += sm.u.d.w2b[j]*tanh_(z);
            }
            sm.u.d.en[er][et] = fmaxf(env, 0.f);
        }
        __syncthreads();
        {   // fused softmax+context: single exp pass, normalize at end
            const int cr = tid >> 5, cup = tid & 31;
            const float* enr = sm.u.d.en[cr];
            float mx = enr[0];
            #pragma unroll
            for (int t2 = 1; t2 < TX; t2++) mx = fmaxf(mx, enr[t2]);
            float ssum = 0.f, s0 = 0.f, s1 = 0.f;
            const u16* ap = &sm.a[cr][0][2*cup];
            #pragma unroll 5
            for (int t2 = 0; t2 < TX; t2++){
                const float e = __expf(enr[t2]-mx);
                const u32 pa = *(const u32*)(ap + t2*72);
                ssum += e;
                s0 += e*lo2f(pa); s1 += e*hi2f(pa);
            }
            const float inv = frcp(ssum);
            s0 *= inv; s1 *= inv;
            const u16 h0 = f2bf(s0), h1 = f2bf(s1);
            const u16 l0 = f2bf(s0 - bf2f_u16(h0)), l1 = f2bf(s1 - bf2f_u16(h1));
            *(u32*)&sm.u.d.ctxh[cr][2*cup] = (u32)h0 | ((u32)h1 << 16);
            *(u32*)&sm.u.d.ctxl[cr][2*cup] = (u32)l0 | ((u32)l1 << 16);
        }
        __syncthreads();
        // z2 = [ctx|s] @ Wp^T + bp   (in-register gates)
        f4 acc2[4];
        #pragma unroll
        for (int gt = 0; gt < 4; gt++) acc2[gt] = (f4){pb4[gt],pb4[gt],pb4[gt],pb4[gt]};
        #pragma unroll
        for (int kt = 0; kt < 2; kt++){
            const int ko = kt*32 + k0q;
            const bool v8 = (mL < 8);
            const short8 ch  = *(const short8*)(v8 ? &sm.u.d.ctxh[mL][ko] : &sm.u.d.zr2[ko]);
            const short8 cl  = *(const short8*)(v8 ? &sm.u.d.ctxl[mL][ko] : &sm.u.d.zr2[ko]);
            const short8 shh = *(const short8*)(v8 ? &sm.u.d.sh[mL][ko]   : &sm.u.d.zr2[ko]);
            const short8 sll = *(const short8*)(v8 ? &sm.u.d.sl[mL][ko]   : &sm.u.d.zr2[ko]);
            #pragma unroll
            for (int gt = 0; gt < 4; gt++){
                acc2[gt] = mfma16(ch,  Bip[gt][kt], acc2[gt]);
                acc2[gt] = mfma16(cl,  Bip[gt][kt], acc2[gt]);
                acc2[gt] = mfma16(shh, Bhp[gt][kt], acc2[gt]);
                acc2[gt] = mfma16(sll, Bhp[gt][kt], acc2[gt]);
            }
        }
        __syncthreads();                                 // frag reads done before s overwrite
        if (qL < 2){
            #pragma unroll
            for (int reg = 0; reg < 4; reg++){
                const int m = qL*4 + reg;
                const float ii = sigm(acc2[0][reg]), ff = sigm(acc2[1][reg]);
                const float gg = tanh_(acc2[2][reg]), oo = sigm(acc2[3][reg]);
                cs2[reg] = ff*cs2[reg] + ii*gg;
                const float sv = oo * tanh_(cs2[reg]);
                const u16 shi = f2bf(sv);
                const u16 slo = f2bf(sv - bf2f_u16(shi));
                sm.u.d.sh[m][uw+mL]  = shi;
                sm.u.d.sl[m][uw+mL]  = slo;
            }
        }
        __syncthreads();
        // out = s @ Wo^T + bo
        f4 acc3 = (f4){boL, boL, boL, boL};
        #pragma unroll
        for (int kt = 0; kt < 2; kt++){
            const int ko = kt*32 + k0q;
            const short8 shh = *(const short8*)((mL < 8) ? &sm.u.d.sh[mL][ko] : &sm.u.d.zr2[ko]);
            const short8 sll = *(const short8*)((mL < 8) ? &sm.u.d.sl[mL][ko] : &sm.u.d.zr2[ko]);
            acc3 = mfma16(shh, Bo2[kt], acc3);
            acc3 = mfma16(sll, Bo2[kt], acc3);
        }
        if (qL < 2){
            #pragma unroll
            for (int reg = 0; reg < 4; reg++){
                const int m = qL*4 + reg;
                out[(((long)(b0+m))*TY + ty)*64 + uw + mL] = acc3[reg];
            }
        }
    }
}

extern "C" void kernel_launch(void* const* d_in, const int* in_sizes, int n_in,
                              void* d_out, int out_size, void* d_ws, size_t ws_size,
                              hipStream_t stream) {
    const float* X    = (const float*)d_in[0];
    const float* Wihf = (const float*)d_in[1];
    const float* Whhf = (const float*)d_in[2];
    const float* bfv  = (const float*)d_in[3];
    const float* Wihr = (const float*)d_in[4];
    const float* Whhr = (const float*)d_in[5];
    const float* brv  = (const float*)d_in[6];
    const float* W1   = (const float*)d_in[7];
    const float* b1   = (const float*)d_in[8];
    const float* W2   = (const float*)d_in[9];
    const float* b2   = (const float*)d_in[10];
    const float* Wihp = (const float*)d_in[11];
    const float* Whhp = (const float*)d_in[12];
    const float* bp   = (const float*)d_in[13];
    const float* Wo   = (const float*)d_in[14];
    const float* bo   = (const float*)d_in[15];
    float* out = (float*)d_out;

    const int B = in_sizes[0] / (TX * 128);
    dim3 grid(B / BT), block(256);
    hipLaunchKernelGGL(fused_kernel, grid, block, 0, stream,
                       X, Wihf, Whhf, bfv, Wihr, Whhr, brv,
                       W1, b1, W2, b2, Wihp, Whhp, bp, Wo, bo, out);
}

// Round 2
// 637.456 us; speedup vs baseline: 1.1811x; 1.1811x over previous
//
#include <hip/hip_runtime.h>

typedef unsigned short u16;
typedef unsigned int   u32;
typedef __attribute__((ext_vector_type(8))) short short8;
typedef __attribute__((ext_vector_type(4))) float f4;

#define BT 8
#define TX 30
#define TY 10

__device__ __forceinline__ float bf2f_u16(u16 h){ u32 i=((u32)h)<<16; float f; __builtin_memcpy(&f,&i,4); return f; }
__device__ __forceinline__ float lo2f(u32 p){ u32 i=p<<16; float f; __builtin_memcpy(&f,&i,4); return f; }
__device__ __forceinline__ float hi2f(u32 p){ u32 i=p&0xffff0000u; float f; __builtin_memcpy(&f,&i,4); return f; }
__device__ __forceinline__ u16 f2bf(float f){ u32 x; __builtin_memcpy(&x,&f,4); u32 r=(x+0x7fffu+((x>>16)&1u))>>16; return (u16)r; }

#if __has_builtin(__builtin_amdgcn_rcpf)
__device__ __forceinline__ float frcp(float x){ return __builtin_amdgcn_rcpf(x); }
#else
__device__ __forceinline__ float frcp(float x){ return 1.0f/x; }
#endif
// fast activations: single v_exp + v_rcp (no fp32 div sequence)
__device__ __forceinline__ float sigm(float x){ return frcp(1.0f+__expf(-x)); }
__device__ __forceinline__ float tanh_(float x){ x=fminf(fmaxf(x,-15.0f),15.0f); float e=__expf(2.0f*x); return 1.0f - 2.0f*frcp(e+1.0f); }

__device__ __forceinline__ f4 mfma16(short8 a, short8 b, f4 c){
    return __builtin_amdgcn_mfma_f32_16x16x32_bf16(a, b, c, 0, 0, 0);
}

union S8u { short8 s; u32 u[4]; };

// pack hi-halves of two fp32 into one u32 (truncated bf16 pair), residual -> lo pair
__device__ __forceinline__ void cvt_pair(float a0, float a1, u32& hp, u32& lp){
    u32 u0, u1; __builtin_memcpy(&u0,&a0,4); __builtin_memcpy(&u1,&a1,4);
    hp = __builtin_amdgcn_perm(u1, u0, 0x07060302u);          // [hi16(a1) : hi16(a0)]
    float r0 = a0 - hi2f(u0);
    float r1 = a1 - hi2f(u1);
    u32 v0, v1; __builtin_memcpy(&v0,&r0,4); __builtin_memcpy(&v1,&r1,4);
    lp = __builtin_amdgcn_perm(v1, v0, 0x07060302u);
}

struct SDec {
    float aW1[BT][TX][10];      // b1 + a @ W1[:, :64].T  (ty-invariant), computed via MFMA
    u16 sh[BT][72], sl[BT][72]; // s hi/lo bf16, A-frag rows 0-7 (rows 8-15 -> zr2)
    u16 ctxh[BT][72], ctxl[BT][72];
    u16 zr2[72];                // always-zero row (decoder A-frag filler for mL>=8)
    float sW1[BT][12];
    float en[BT][32];
    float w2b[12]; float b2s;
};
struct SEnc {
    u16 h[2][2][2][BT][40];     // [parity][dir][hi/lo][m][k], K=32 pad 40
    u16 zr[40];                 // always-zero row (A-frag filler)
};
union UU { SEnc e; SDec d; };
struct Smem {
    u16 a[BT][TX][72];          // encoder outputs bf16 (pad 72: 144B rows keep 16B align)
    UU u;
};
// LDS: 34560 + max(5200, 15812) ~= 50.4 KB -> 3 blocks/CU (LDS-limited)
// launch_bounds(256,2): do NOT force 3 waves/EU on the allocator — round 1 showed
// that floor spills ~845 B/thread to scratch (WRITE_SIZE 41->289 MB, dur +25%).
// At the natural ~128 VGPR allocation the HW still co-schedules 3 blocks/CU.

__global__ __launch_bounds__(256, 2) void fused_kernel(
    const float* __restrict__ X,
    const float* __restrict__ Wihf, const float* __restrict__ Whhf, const float* __restrict__ bfv,
    const float* __restrict__ Wihr, const float* __restrict__ Whhr, const float* __restrict__ brv,
    const float* __restrict__ W1, const float* __restrict__ b1, const float* __restrict__ W2, const float* __restrict__ b2,
    const float* __restrict__ Wihp, const float* __restrict__ Whhp, const float* __restrict__ bp,
    const float* __restrict__ Wo, const float* __restrict__ bo,
    float* __restrict__ out)
{
    __shared__ __align__(16) Smem sm;
    const int tid = threadIdx.x;
    const int b0  = blockIdx.x * BT;

    {   // zero only the encoder union region (h bufs + zr must start 0)
        u32* p = (u32*)&sm.u.e;
        for (int i = tid; i < (int)(sizeof(SEnc)/4); i += 256) p[i] = 0u;
    }
    __syncthreads();

    const int lane = tid & 63;
    const int wv   = tid >> 6;     // wave 0..3
    const int mL   = lane & 15;    // frag non-K index
    const int qL   = lane >> 4;    // quad
    const int k0q  = qL * 8;
    const int ed   = wv >> 1;      // encoder dir
    const int ub   = (wv & 1) * 16;// encoder unit base within NA=32
    const int sstep= mL >> 3;      // 0: step t rows, 1: step t+1 rows

    // ===================== encoder =====================
    const float* Wih = ed ? Wihr : Wihf;
    const float* Whh = ed ? Whhr : Whhf;
    const float* bv  = ed ? brv  : bfv;

    short8 Bih[4][4]; short8 Bhh[4]; float bias4[4];
    #pragma unroll
    for (int gt = 0; gt < 4; gt++){
        const int n = gt*32 + ub + mL;                  // gate row (i,f,g,o chunks of 32)
        #pragma unroll
        for (int kt = 0; kt < 4; kt++){
            const float* p = Wih + n*128 + kt*32 + k0q;
            short8 s;
            #pragma unroll
            for (int j = 0; j < 8; j++) s[j] = (short)f2bf(p[j]);
            Bih[gt][kt] = s;
        }
        {
            const float* p = Whh + n*32 + k0q;
            short8 s;
            #pragma unroll
            for (int j = 0; j < 8; j++) s[j] = (short)f2bf(p[j]);
            Bhh[gt] = s;
        }
        bias4[gt] = bv[n];
    }

    const float* xrow = X + ((long)(b0 + (mL & 7))) * TX * 128;  // rows 8-15: same batch row, step t+1
    float cst[4] = {0.f,0.f,0.f,0.f};  // c-state: lives in qL<2 lanes before even steps, swaps via shfl_xor 32

    // pair processor: steps (t, t+1); M rows 0-7 = step t, 8-15 = step t+1
    auto epair = [&](int t, f4* cur, f4* nxt){
        if (t + 2 < TX){                                 // prefetch next pair
            const int ts = ed ? (TX-1-(t+2+sstep)) : (t+2+sstep);
            const float* p = xrow + ts*128 + k0q;
            #pragma unroll
            for (int kt = 0; kt < 4; kt++){
                nxt[2*kt]   = *(const f4*)(p + kt*32);
                nxt[2*kt+1] = *(const f4*)(p + kt*32 + 4);
            }
        }
        const int rb = (t+1) & 1, wb = t & 1;            // h_{t-1} in buf rb; h_t -> buf wb; h_{t+1} -> buf rb

        f4 acc[4];
        #pragma unroll
        for (int gt = 0; gt < 4; gt++) acc[gt] = (f4){bias4[gt],bias4[gt],bias4[gt],bias4[gt]};

        #pragma unroll
        for (int kt = 0; kt < 4; kt++){                  // x-GEMM, both steps at once
            S8u xh, xl;
            #pragma unroll
            for (int pp = 0; pp < 4; pp++){
                const f4 v = cur[2*kt + (pp>>1)];
                const int e = (pp & 1) * 2;
                cvt_pair(v[e], v[e+1], xh.u[pp], xl.u[pp]);
            }
            #pragma unroll
            for (int gt = 0; gt < 4; gt++){
                acc[gt] = mfma16(xh.s, Bih[gt][kt], acc[gt]);
                acc[gt] = mfma16(xl.s, Bih[gt][kt], acc[gt]);
            }
        }
        {   // h-MFMA step t: A rows 0-7 = h_{t-1}, rows 8-15 = 0
            const short8 Ahh = *(const short8*)((mL < 8) ? &sm.u.e.h[rb][ed][0][mL][k0q] : &sm.u.e.zr[k0q]);
            const short8 Ahl = *(const short8*)((mL < 8) ? &sm.u.e.h[rb][ed][1][mL][k0q] : &sm.u.e.zr[k0q]);
            #pragma unroll
            for (int gt = 0; gt < 4; gt++){
                acc[gt] = mfma16(Ahh, Bhh[gt], acc[gt]);
                acc[gt] = mfma16(Ahl, Bhh[gt], acc[gt]);
            }
        }
        if (qL < 2){                                     // cell update step t (rows 0-7)
            const int tpos = ed ? (TX-1-t) : t;
            #pragma unroll
            for (int reg = 0; reg < 4; reg++){
                const int m = qL*4 + reg;
                const float ii = sigm(acc[0][reg]), ff = sigm(acc[1][reg]);
                const float gg = tanh_(acc[2][reg]), oo = sigm(acc[3][reg]);
                cst[reg] = ff*cst[reg] + ii*gg;
                const float hh = oo * tanh_(cst[reg]);
                const u16 hhi = f2bf(hh);
                const u16 hlo = f2bf(hh - bf2f_u16(hhi));
                sm.u.e.h[wb][ed][0][m][ub+mL] = hhi;
                sm.u.e.h[wb][ed][1][m][ub+mL] = hlo;
                sm.a[m][tpos][ed*32 + ub + mL] = hhi;
            }
        }
        #pragma unroll
        for (int reg = 0; reg < 4; reg++) cst[reg] = __shfl_xor(cst[reg], 32);  // c -> qL>=2 lanes
        __syncthreads();
        {   // h-MFMA step t+1: A rows 8-15 = h_t, rows 0-7 = 0
            const short8 Ahh = *(const short8*)((mL >= 8) ? &sm.u.e.h[wb][ed][0][mL-8][k0q] : &sm.u.e.zr[k0q]);
            const short8 Ahl = *(const short8*)((mL >= 8) ? &sm.u.e.h[wb][ed][1][mL-8][k0q] : &sm.u.e.zr[k0q]);
            #pragma unroll
            for (int gt = 0; gt < 4; gt++){
                acc[gt] = mfma16(Ahh, Bhh[gt], acc[gt]);
                acc[gt] = mfma16(Ahl, Bhh[gt], acc[gt]);
            }
        }
        if (qL >= 2){                                    // cell update step t+1 (rows 8-15)
            const int tpos = ed ? (TX-2-t) : (t+1);
            #pragma unroll
            for (int reg = 0; reg < 4; reg++){
                const int m = (qL-2)*4 + reg;
                const float ii = sigm(acc[0][reg]), ff = sigm(acc[1][reg]);
                const float gg = tanh_(acc[2][reg]), oo = sigm(acc[3][reg]);
                cst[reg] = ff*cst[reg] + ii*gg;
                const float hh = oo * tanh_(cst[reg]);
                const u16 hhi = f2bf(hh);
                const u16 hlo = f2bf(hh - bf2f_u16(hhi));
                sm.u.e.h[rb][ed][0][m][ub+mL] = hhi;
                sm.u.e.h[rb][ed][1][m][ub+mL] = hlo;
                sm.a[m][tpos][ed*32 + ub + mL] = hhi;
            }
        }
        #pragma unroll
        for (int reg = 0; reg < 4; reg++) cst[reg] = __shfl_xor(cst[reg], 32);  // c -> qL<2 lanes
        __syncthreads();
    };

    f4 rawA[8], rawB[8];
    {   // initial pair load
        const int ts0 = ed ? (TX-1-sstep) : sstep;
        const float* p = xrow + ts0*128 + k0q;
        #pragma unroll
        for (int kt = 0; kt < 4; kt++){
            rawA[2*kt]   = *(const f4*)(p + kt*32);
            rawA[2*kt+1] = *(const f4*)(p + kt*32 + 4);
        }
    }
    for (int tp = 0; tp < 28; tp += 4){ epair(tp, rawA, rawB); epair(tp+2, rawB, rawA); }
    epair(28, rawA, rawB);                               // last pair (no prefetch)

    // ===================== decoder setup =====================
    {   // zero sh, sl, ctxh, ctxl, zr2 (contiguous block)
        u32* z = (u32*)sm.u.d.sh;
        for (int i = tid; i < (4*BT*72 + 72)/2; i += 256) z[i] = 0u;
    }
    if (tid < 10) sm.u.d.w2b[tid] = W2[tid];
    if (tid == 0) sm.u.d.b2s = b2[0];

    // B-frags for aW1 = b1 + a @ W1[:, :64].T  (hi/lo split of W1 for fp32-class accuracy)
    short8 W1aB[2][2];
    #pragma unroll
    for (int kt = 0; kt < 2; kt++){
        short8 hv8, lv8;
        #pragma unroll
        for (int j = 0; j < 8; j++){
            const float v = (mL < 10) ? W1[mL*128 + kt*32 + k0q + j] : 0.f;
            const u16 hb = f2bf(v);
            hv8[j] = (short)hb;
            lv8[j] = (short)f2bf(v - bf2f_u16(hb));
        }
        W1aB[kt][0] = hv8; W1aB[kt][1] = lv8;
    }
    const float b1v = (mL < 10) ? b1[mL] : 0.f;

    // aW1 via MFMA: M=240 rows (r = b*30 + t), N=10, K=64; a rows contiguous at stride 72 u16
    for (int tile = wv; tile < 15; tile += 4){
        f4 accA = (f4){b1v, b1v, b1v, b1v};
        const u16* abase = &sm.a[0][0][0] + (tile*16 + mL)*72;
        #pragma unroll
        for (int kt = 0; kt < 2; kt++){
            const short8 av = *(const short8*)(abase + kt*32 + k0q);
            accA = mfma16(av, W1aB[kt][0], accA);
            accA = mfma16(av, W1aB[kt][1], accA);
        }
        if (mL < 10){
            #pragma unroll
            for (int reg = 0; reg < 4; reg++){
                const int r = tile*16 + qL*4 + reg;      // r < 240 always (15*16 = 240)
                (&sm.u.d.aW1[0][0][0])[r*10 + mL] = accA[reg];
            }
        }
    }

    const int uw = wv * 16;                              // decoder unit base (NS=64 over 4 waves)
    short8 Bip[4][2], Bhp[4][2]; float pb4[4];
    #pragma unroll
    for (int gt = 0; gt < 4; gt++){
        const int n = gt*64 + uw + mL;                   // post-cell gate row (chunks of 64)
        #pragma unroll
        for (int kt = 0; kt < 2; kt++){
            const float* p = Wihp + n*64 + kt*32 + k0q;
            const float* q = Whhp + n*64 + kt*32 + k0q;
            short8 s1v, s2v;
            #pragma unroll
            for (int j = 0; j < 8; j++){ s1v[j] = (short)f2bf(p[j]); s2v[j] = (short)f2bf(q[j]); }
            Bip[gt][kt] = s1v; Bhp[gt][kt] = s2v;
        }
        pb4[gt] = bp[n];
    }
    short8 Bo2[2];
    {
        const int n = uw + mL;
        #pragma unroll
        for (int kt = 0; kt < 2; kt++){
            const float* p = Wo + n*64 + kt*32 + k0q;
            short8 s;
            #pragma unroll
            for (int j = 0; j < 8; j++) s[j] = (short)f2bf(p[j]);
            Bo2[kt] = s;
        }
    }
    short8 W1sB[2];                                      // B-frag of W1[:,64:128], n=mL (rows>=10 zero)
    #pragma unroll
    for (int kt = 0; kt < 2; kt++){
        short8 s;
        #pragma unroll
        for (int j = 0; j < 8; j++){
            const float v = (mL < 10) ? W1[mL*128 + 64 + kt*32 + k0q + j] : 0.f;
            s[j] = (short)f2bf(v);
        }
        W1sB[kt] = s;
    }
    const float boL = bo[uw + mL];
    float cs2[4] = {0.f,0.f,0.f,0.f};
    __syncthreads();

    // ===================== decoder loop =====================
    for (int ty = 0; ty < TY; ty++){
        {   // sW1 = s @ W1[:,64:].T via MFMA (4 MFMAs, all waves redundantly)
            f4 accW = (f4){0.f,0.f,0.f,0.f};
            #pragma unroll
            for (int kt = 0; kt < 2; kt++){
                const int ko = kt*32 + k0q;
                const short8 shh = *(const short8*)((mL < 8) ? &sm.u.d.sh[mL][ko] : &sm.u.d.zr2[ko]);
                const short8 sll = *(const short8*)((mL < 8) ? &sm.u.d.sl[mL][ko] : &sm.u.d.zr2[ko]);
                accW = mfma16(shh, W1sB[kt], accW);
                accW = mfma16(sll, W1sB[kt], accW);
            }
            if (qL < 2 && mL < 10 && wv == 0){
                #pragma unroll
                for (int reg = 0; reg < 4; reg++) sm.u.d.sW1[qL*4+reg][mL] = accW[reg];
            }
        }
        __syncthreads();
        if (tid < 240){                                  // en = relu(tanh(aW1+sW1) . w2 + b2)
            const int er = tid/30, et = tid - er*30;
            float env = sm.u.d.b2s;
            #pragma unroll
            for (int j = 0; j < 10; j++){
                const float z = sm.u.d.aW1[er][et][j] + sm.u.d.sW1[er][j];
                env += sm.u.d.w2b[j]*tanh_(z);
            }
            sm.u.d.en[er][et] = fmaxf(env, 0.f);
        }
        __syncthreads();
        {   // fused softmax+context: single exp pass, normalize at end
            const int cr = tid >> 5, cup = tid & 31;
            const float* enr = sm.u.d.en[cr];
            float mx = enr[0];
            #pragma unroll
            for (int t2 = 1; t2 < TX; t2++) mx = fmaxf(mx, enr[t2]);
            float ssum = 0.f, s0 = 0.f, s1 = 0.f;
            const u16* ap = &sm.a[cr][0][2*cup];
            #pragma unroll 5
            for (int t2 = 0; t2 < TX; t2++){
                const float e = __expf(enr[t2]-mx);
                const u32 pa = *(const u32*)(ap + t2*72);
                ssum += e;
                s0 += e*lo2f(pa); s1 += e*hi2f(pa);
            }
            const float inv = frcp(ssum);
            s0 *= inv; s1 *= inv;
            const u16 h0 = f2bf(s0), h1 = f2bf(s1);
            const u16 l0 = f2bf(s0 - bf2f_u16(h0)), l1 = f2bf(s1 - bf2f_u16(h1));
            *(u32*)&sm.u.d.ctxh[cr][2*cup] = (u32)h0 | ((u32)h1 << 16);
            *(u32*)&sm.u.d.ctxl[cr][2*cup] = (u32)l0 | ((u32)l1 << 16);
        }
        __syncthreads();
        // z2 = [ctx|s] @ Wp^T + bp   (in-register gates)
        f4 acc2[4];
        #pragma unroll
        for (int gt = 0; gt < 4; gt++) acc2[gt] = (f4){pb4[gt],pb4[gt],pb4[gt],pb4[gt]};
        #pragma unroll
        for (int kt = 0; kt < 2; kt++){
            const int ko = kt*32 + k0q;
            const bool v8 = (mL < 8);
            const short8 ch  = *(const short8*)(v8 ? &sm.u.d.ctxh[mL][ko] : &sm.u.d.zr2[ko]);
            const short8 cl  = *(const short8*)(v8 ? &sm.u.d.ctxl[mL][ko] : &sm.u.d.zr2[ko]);
            const short8 shh = *(const short8*)(v8 ? &sm.u.d.sh[mL][ko]   : &sm.u.d.zr2[ko]);
            const short8 sll = *(const short8*)(v8 ? &sm.u.d.sl[mL][ko]   : &sm.u.d.zr2[ko]);
            #pragma unroll
            for (int gt = 0; gt < 4; gt++){
                acc2[gt] = mfma16(ch,  Bip[gt][kt], acc2[gt]);
                acc2[gt] = mfma16(cl,  Bip[gt][kt], acc2[gt]);
                acc2[gt] = mfma16(shh, Bhp[gt][kt], acc2[gt]);
                acc2[gt] = mfma16(sll, Bhp[gt][kt], acc2[gt]);
            }
        }
        __syncthreads();                                 // frag reads done before s overwrite
        if (qL < 2){
            #pragma unroll
            for (int reg = 0; reg < 4; reg++){
                const int m = qL*4 + reg;
                const float ii = sigm(acc2[0][reg]), ff = sigm(acc2[1][reg]);
                const float gg = tanh_(acc2[2][reg]), oo = sigm(acc2[3][reg]);
                cs2[reg] = ff*cs2[reg] + ii*gg;
                const float sv = oo * tanh_(cs2[reg]);
                const u16 shi = f2bf(sv);
                const u16 slo = f2bf(sv - bf2f_u16(shi));
                sm.u.d.sh[m][uw+mL]  = shi;
                sm.u.d.sl[m][uw+mL]  = slo;
            }
        }
        __syncthreads();
        // out = s @ Wo^T + bo
        f4 acc3 = (f4){boL, boL, boL, boL};
        #pragma unroll
        for (int kt = 0; kt < 2; kt++){
            const int ko = kt*32 + k0q;
            const short8 shh = *(const short8*)((mL < 8) ? &sm.u.d.sh[mL][ko] : &sm.u.d.zr2[ko]);
            const short8 sll = *(const short8*)((mL < 8) ? &sm.u.d.sl[mL][ko] : &sm.u.d.zr2[ko]);
            acc3 = mfma16(shh, Bo2[kt], acc3);
            acc3 = mfma16(sll, Bo2[kt], acc3);
        }
        if (qL < 2){
            #pragma unroll
            for (int reg = 0; reg < 4; reg++){
                const int m = qL*4 + reg;
                out[(((long)(b0+m))*TY + ty)*64 + uw + mL] = acc3[reg];
            }
        }
    }
}

extern "C" void kernel_launch(void* const* d_in, const int* in_sizes, int n_in,
                              void* d_out, int out_size, void* d_ws, size_t ws_size,
                              hipStream_t stream) {
    const float* X    = (const float*)d_in[0];
    const float* Wihf = (const float*)d_in[1];
    const float* Whhf = (const float*)d_in[2];
    const float* bfv  = (const float*)d_in[3];
    const float* Wihr = (const float*)d_in[4];
    const float* Whhr = (const float*)d_in[5];
    const float* brv  = (const float*)d_in[6];
    const float* W1   = (const float*)d_in[7];
    const float* b1   = (const float*)d_in[8];
    const float* W2   = (const float*)d_in[9];
    const float* b2   = (const float*)d_in[10];
    const float* Wihp = (const float*)d_in[11];
    const float* Whhp = (const float*)d_in[12];
    const float* bp   = (const float*)d_in[13];
    const float* Wo   = (const float*)d_in[14];
    const float* bo   = (const float*)d_in[15];
    float* out = (float*)d_out;

    const int B = in_sizes[0] / (TX * 128);
    dim3 grid(B / BT), block(256);
    hipLaunchKernelGGL(fused_kernel, grid, block, 0, stream,
                       X, Wihf, Whhf, bfv, Wihr, Whhr, brv,
                       W1, b1, W2, b2, Wihp, Whhp, bp, Wo, bo, out);
}